// Round 3
// baseline (294.535 us; speedup 1.0000x reference)
//
#include <hip/hip_runtime.h>
#include <hip/hip_bf16.h>

#define BM 128
#define BN 128
#define BK 32
#define TB 256
#define LDK 40   // padded LDS row stride (80 B): b128 frag reads conflict-free,
                 // b64 slab writes <=2-way (free per m136)
#define KSTEPS 16

typedef __attribute__((ext_vector_type(8))) short bf16x8;
typedef __attribute__((ext_vector_type(4))) float f32x4;
typedef __attribute__((ext_vector_type(2))) int   i32x2;

static __device__ inline int pk2(float a, float b) {
    // two fp32 -> packed bf16 (RNE)
    __hip_bfloat162 h = __float22bfloat162_rn(float2{a, b});
    int r;
    __builtin_memcpy(&r, &h, 4);
    return r;
}

// Raw workgroup barrier WITHOUT __syncthreads()'s vmcnt(0) drain.
// LDS ordering only needs lgkmcnt(0); register-destined global prefetch
// loads deliberately stay in flight across the barrier (the whole point).
// sched_barrier(0) stops the scheduler hoisting next-phase ds_reads above
// the s_barrier (they'd race other waves' ds_writes).
#define BARRIER() do {                                         \
    asm volatile("s_waitcnt lgkmcnt(0)" ::: "memory");         \
    __builtin_amdgcn_s_barrier();                              \
    __builtin_amdgcn_sched_barrier(0);                         \
} while (0)

// 4 x f32x4 global loads for one tile-slab (X or W side)
#define LOAD_X(dst, t) do {                                                     \
    _Pragma("unroll")                                                           \
    for (int i = 0; i < 4; ++i)                                                 \
        dst[i] = *(const f32x4*)(xg + (size_t)i * 32 * 512 + (t) * BK);         \
} while (0)

#define LOAD_W(t) do {                                                          \
    _Pragma("unroll")                                                           \
    for (int i = 0; i < 4; ++i)                                                 \
        wx[i] = *(const f32x4*)(wg + (size_t)i * 32 * 512 + (t) * BK);          \
} while (0)

// convert + LDS-store one staged tile (X from xsrc regs, W from wx regs)
#define STORE_TILE(xsrc, buf) do {                                              \
    _Pragma("unroll")                                                           \
    for (int i = 0; i < 4; ++i) {                                               \
        i32x2 pa; pa[0] = pk2(xsrc[i][0], xsrc[i][1]);                          \
                  pa[1] = pk2(xsrc[i][2], xsrc[i][3]);                          \
        *(i32x2*)&As[buf][(i * 32 + lrow) * LDK + lcol] = pa;                   \
        i32x2 pb; pb[0] = pk2(wx[i][0], wx[i][1]);                              \
                  pb[1] = pk2(wx[i][2], wx[i][3]);                              \
        *(i32x2*)&Bs[buf][(i * 32 + lrow) * LDK + lcol] = pb;                   \
    }                                                                           \
} while (0)

// One K-step. P = ks&1 (compile-time), AXI = X reg-set receiving tile ks+2,
// AXC = X reg-set holding tile ks+1 (consumed here). Static set names keep
// everything in registers (runtime-indexed ext_vector arrays go to scratch).
// Issue order W(ks+1) then X(ks+2): at consume time the counted waits become
// vmcnt(8)/vmcnt(4), leaving the 4 X(ks+2) loads outstanding across BARRIER.
#define KITER(ks, P, AXI, AXC) do {                                             \
    if ((ks) + 1 < KSTEPS) LOAD_W((ks) + 1);                                    \
    if ((ks) + 2 < KSTEPS) LOAD_X(AXI, (ks) + 2);                               \
    bf16x8 af[4], bfr[4];                                                       \
    _Pragma("unroll")                                                           \
    for (int mf = 0; mf < 4; ++mf)                                              \
        af[mf] = *(const bf16x8*)&As[P][(wm + mf * 16 + frow) * LDK + fk];      \
    _Pragma("unroll")                                                           \
    for (int nf = 0; nf < 4; ++nf)                                              \
        bfr[nf] = *(const bf16x8*)&Bs[P][(wn + nf * 16 + frow) * LDK + fk];     \
    _Pragma("unroll")                                                           \
    for (int mf = 0; mf < 4; ++mf)                                              \
        _Pragma("unroll")                                                       \
        for (int nf = 0; nf < 4; ++nf)                                          \
            acc[mf][nf] = __builtin_amdgcn_mfma_f32_16x16x32_bf16(              \
                af[mf], bfr[nf], acc[mf][nf], 0, 0, 0);                         \
    if ((ks) + 1 < KSTEPS) {                                                    \
        STORE_TILE(AXC, (P) ^ 1);                                               \
        BARRIER();                                                              \
    }                                                                           \
} while (0)

__global__ __launch_bounds__(TB) void bgemm_bt_bias(
    const float* __restrict__ X,     // [8, 8192, 512]
    const float* __restrict__ Wt,    // [8, 512, 512]
    const float* __restrict__ Bias,  // [8, 512]
    float* __restrict__ Out)         // [8, 8192, 512]
{
    // XCD-aware swizzle: 4 n-tiles sharing an x-panel land on one XCD
    const int flat  = blockIdx.x;          // 0..2047
    const int xcd   = flat & 7;
    const int rr    = flat >> 3;
    const int nt    = rr & 3;
    const int p     = rr >> 2;
    const int panel = p * 8 + xcd;
    const int mt    = panel & 63;
    const int b     = panel >> 6;

    const int m0  = mt * BM;
    const int n0  = nt * BN;
    const int tid = threadIdx.x;
    const int lane = tid & 63;
    const int wave = tid >> 6;
    const int wm = (wave >> 1) * 64;
    const int wn = (wave & 1) * 64;

    __shared__ short As[2][BM * LDK];
    __shared__ short Bs[2][BN * LDK];

    // slab-coalesced staging: thread t, chunk i -> row i*32+(t>>3), 16B at col (t&7)*4
    const int lrow = tid >> 3;         // 0..31
    const int lcol = (tid & 7) * 4;    // float col within the 32-float K chunk

    const float* xg = X  + ((size_t)b * 8192 + m0 + lrow) * 512 + lcol;
    const float* wg = Wt + ((size_t)b * 512  + n0 + lrow) * 512 + lcol;

    // X prefetch depth-2 (two named sets), W depth-1 (L2-resident panel)
    f32x4 ax0[4], ax1[4], wx[4];

    const int frow = lane & 15;
    const int fk   = (lane >> 4) * 8;

    // ---- prologue ----
    LOAD_X(ax0, 0);
    LOAD_W(0);
    STORE_TILE(ax0, 0);     // one-time full vmcnt wait
    LOAD_X(ax1, 1);         // tile 1 X in flight across prologue barrier
    BARRIER();

    f32x4 acc[4][4];
#pragma unroll
    for (int i = 0; i < 4; ++i)
#pragma unroll
        for (int j = 0; j < 4; ++j)
            acc[i][j] = (f32x4){0.f, 0.f, 0.f, 0.f};

    // ---- main loop: 2-unrolled so set/buffer parity is compile-time ----
    for (int ks = 0; ks < KSTEPS; ks += 2) {
        KITER(ks,     0, ax0, ax1);
        KITER(ks + 1, 1, ax1, ax0);
    }

    // ---- epilogue: add bias, store fp32 ----
    float bv[4];
    const float* biasp = Bias + (size_t)b * 512 + n0 + wn;
#pragma unroll
    for (int nf = 0; nf < 4; ++nf)
        bv[nf] = biasp[nf * 16 + frow];

    float* outp = Out + ((size_t)b * 8192 + m0 + wm) * 512 + n0 + wn;
    const int orow = (lane >> 4) * 4;   // C/D: row = (lane>>4)*4 + reg
#pragma unroll
    for (int mf = 0; mf < 4; ++mf)
#pragma unroll
        for (int nf = 0; nf < 4; ++nf)
#pragma unroll
            for (int r = 0; r < 4; ++r)
                outp[(size_t)(mf * 16 + orow + r) * 512 + nf * 16 + frow] =
                    acc[mf][nf][r] + bv[nf];
}

extern "C" void kernel_launch(void* const* d_in, const int* in_sizes, int n_in,
                              void* d_out, int out_size, void* d_ws, size_t ws_size,
                              hipStream_t stream) {
    const float* X    = (const float*)d_in[0];
    const float* Wt   = (const float*)d_in[1];
    const float* Bias = (const float*)d_in[2];
    float* Out        = (float*)d_out;

    dim3 grid(2048);
    bgemm_bt_bias<<<grid, TB, 0, stream>>>(X, Wt, Bias, Out);
}

// Round 4
// 286.675 us; speedup vs baseline: 1.0274x; 1.0274x over previous
//
#include <hip/hip_runtime.h>
#include <hip/hip_bf16.h>

#define BM 128
#define BN 128
#define BK 32
#define TB 256
#define LDK 34   // padded LDS row stride (68 B = 17 banks, coprime with 32):
                 // frag-read rows hit 16 distinct start banks (better than LDK=40's
                 // gcd-4 aliasing), and LDS/block drops 40960->34816 B so 4 blocks/CU
                 // fit with headroom (40960*4 was exactly 160 KiB -> only 3 resident)

typedef __attribute__((ext_vector_type(8))) short bf16x8;
typedef __attribute__((ext_vector_type(4))) float f32x4;
typedef __attribute__((ext_vector_type(2))) int   i32x2;

static __device__ inline int pk2(float a, float b) {
    // two fp32 -> packed bf16 (RNE)
    __hip_bfloat162 h = __float22bfloat162_rn(float2{a, b});
    int r;
    __builtin_memcpy(&r, &h, 4);
    return r;
}

__global__ __launch_bounds__(TB) void bgemm_bt_bias(
    const float* __restrict__ X,     // [8, 8192, 512]
    const float* __restrict__ Wt,    // [8, 512, 512]
    const float* __restrict__ Bias,  // [8, 512]
    float* __restrict__ Out)         // [8, 8192, 512]
{
    // XCD-aware swizzle: 4 n-tiles sharing an x-panel land on one XCD (R2 win: FETCH 270->103MB)
    const int flat  = blockIdx.x;          // 0..2047
    const int xcd   = flat & 7;
    const int rr    = flat >> 3;
    const int nt    = rr & 3;
    const int p     = rr >> 2;
    const int panel = p * 8 + xcd;
    const int mt    = panel & 63;
    const int b     = panel >> 6;

    const int m0  = mt * BM;
    const int n0  = nt * BN;
    const int tid = threadIdx.x;
    const int lane = tid & 63;
    const int wave = tid >> 6;
    const int wm = (wave >> 1) * 64;
    const int wn = (wave & 1) * 64;

    __shared__ short As[2][BM * LDK];
    __shared__ short Bs[2][BN * LDK];

    // ---- slab-coalesced staging: thread t, chunk i -> row i*32+(t>>3), 16B at col (t&7)*4 floats.
    // Per load instr: 8 rows x 128 B contiguous = fully coalesced (16 lines/KB, was 64).
    const int lrow = tid >> 3;         // 0..31
    const int lcol = (tid & 7) * 4;    // float col within the 32-float K chunk

    const float* xg = X  + ((size_t)b * 8192 + m0 + lrow) * 512 + lcol;
    const float* wg = Wt + ((size_t)b * 512  + n0 + lrow) * 512 + lcol;
    // chunk i adds i*32 rows = i*32*512 floats; K-step ks adds ks*32 floats

    f32x4 ax[4], bx[4];

    // ---- prologue: tile 0 -> buf 0 ----
    {
#pragma unroll
        for (int i = 0; i < 4; ++i) {
            ax[i] = *(const f32x4*)(xg + (size_t)i * 32 * 512);
            bx[i] = *(const f32x4*)(wg + (size_t)i * 32 * 512);
        }
#pragma unroll
        for (int i = 0; i < 4; ++i) {
            i32x2 pa; pa[0] = pk2(ax[i][0], ax[i][1]); pa[1] = pk2(ax[i][2], ax[i][3]);
            *(i32x2*)&As[0][(i * 32 + lrow) * LDK + lcol] = pa;
            i32x2 pb; pb[0] = pk2(bx[i][0], bx[i][1]); pb[1] = pk2(bx[i][2], bx[i][3]);
            *(i32x2*)&Bs[0][(i * 32 + lrow) * LDK + lcol] = pb;
        }
    }
    __syncthreads();

    f32x4 acc[4][4];
#pragma unroll
    for (int i = 0; i < 4; ++i)
#pragma unroll
        for (int j = 0; j < 4; ++j)
            acc[i][j] = (f32x4){0.f, 0.f, 0.f, 0.f};

    const int frow = lane & 15;
    const int fk   = (lane >> 4) * 8;

    const int KSTEPS = 512 / BK;   // 16
#pragma unroll 2
    for (int ks = 0; ks < KSTEPS; ++ks) {
        const int cur = ks & 1;
        const int nxt = cur ^ 1;

        // issue next tile's (coalesced) loads right after the barrier; consumed
        // after the MFMA section so ds_read+MFMA cover the L2 latency
        if (ks + 1 < KSTEPS) {
#pragma unroll
            for (int i = 0; i < 4; ++i) {
                ax[i] = *(const f32x4*)(xg + (size_t)i * 32 * 512 + (ks + 1) * BK);
                bx[i] = *(const f32x4*)(wg + (size_t)i * 32 * 512 + (ks + 1) * BK);
            }
        }

        bf16x8 af[4], bfr[4];
#pragma unroll
        for (int mf = 0; mf < 4; ++mf)
            af[mf] = *(const bf16x8*)&As[cur][(wm + mf * 16 + frow) * LDK + fk];
#pragma unroll
        for (int nf = 0; nf < 4; ++nf)
            bfr[nf] = *(const bf16x8*)&Bs[cur][(wn + nf * 16 + frow) * LDK + fk];

#pragma unroll
        for (int mf = 0; mf < 4; ++mf)
#pragma unroll
            for (int nf = 0; nf < 4; ++nf)
                acc[mf][nf] = __builtin_amdgcn_mfma_f32_16x16x32_bf16(
                    af[mf], bfr[nf], acc[mf][nf], 0, 0, 0);

        if (ks + 1 < KSTEPS) {
#pragma unroll
            for (int i = 0; i < 4; ++i) {
                i32x2 pa; pa[0] = pk2(ax[i][0], ax[i][1]); pa[1] = pk2(ax[i][2], ax[i][3]);
                *(i32x2*)&As[nxt][(i * 32 + lrow) * LDK + lcol] = pa;
                i32x2 pb; pb[0] = pk2(bx[i][0], bx[i][1]); pb[1] = pk2(bx[i][2], bx[i][3]);
                *(i32x2*)&Bs[nxt][(i * 32 + lrow) * LDK + lcol] = pb;
            }
        }

        __syncthreads();
    }

    // ---- epilogue: add bias, store fp32 ----
    // each quarter-wave (16 lanes, frow 0..15) writes one full aligned 64-B line:
    // line-request count already minimal; no LDS staging needed
    float bv[4];
    const float* biasp = Bias + (size_t)b * 512 + n0 + wn;
#pragma unroll
    for (int nf = 0; nf < 4; ++nf)
        bv[nf] = biasp[nf * 16 + frow];

    float* outp = Out + ((size_t)b * 8192 + m0 + wm) * 512 + n0 + wn;
    const int orow = (lane >> 4) * 4;   // C/D: row = (lane>>4)*4 + reg
#pragma unroll
    for (int mf = 0; mf < 4; ++mf)
#pragma unroll
        for (int nf = 0; nf < 4; ++nf)
#pragma unroll
            for (int r = 0; r < 4; ++r)
                outp[(size_t)(mf * 16 + orow + r) * 512 + nf * 16 + frow] =
                    acc[mf][nf][r] + bv[nf];
}

extern "C" void kernel_launch(void* const* d_in, const int* in_sizes, int n_in,
                              void* d_out, int out_size, void* d_ws, size_t ws_size,
                              hipStream_t stream) {
    const float* X    = (const float*)d_in[0];
    const float* Wt   = (const float*)d_in[1];
    const float* Bias = (const float*)d_in[2];
    float* Out        = (float*)d_out;

    dim3 grid(2048);
    bgemm_bt_bias<<<grid, TB, 0, stream>>>(X, Wt, Bias, Out);
}